// Round 4
// baseline (120.092 us; speedup 1.0000x reference)
//
#include <hip/hip_runtime.h>

#define NB 128      // batch
#define NT 4096     // T
#define DKD 16      // d_k == d_q
#define DW 32       // d_w
#define CHUNKS 16   // T chunks -> 2048 blocks ~ 6 blocks/CU (24 waves/CU)
#define TC 256      // NT / CHUNKS
#define BLK 256
#define BLK2 128    // finish kernel block

__device__ __forceinline__ float fast_tanh(float x) {
    // tanh(x) = 1 - 2/(e^{2x}+1); exact at +/-inf limits, ~1 ulp rcp error.
    float e = __expf(2.0f * x);
    return 1.0f - 2.0f * __builtin_amdgcn_rcpf(e + 1.0f);
}

// Kernel 1: per (batch, chunk) block, ONE t per thread (t = tid).
// p = exp(score) with no max-subtract (|score| <= ||v_w||_1+|v_b| ~ 2.6 since
// tanh is bounded). Writes unnormalized p; reduces per-chunk l, ctx to ws.
//
// R4 structure: every global load is short-lived and immediately consumed
// (4 independent k float4s -> one wait -> w-loop; 4 independent v float4s ->
// one wait -> ctx). Latency hidden by occupancy (launch_bounds(256,6) ~ 24
// waves/CU), not by long prefetch live-ranges the allocator would sink.
__global__ __launch_bounds__(BLK, 6) void aa_score(
    const float* __restrict__ query, const float* __restrict__ key,
    const float* __restrict__ value, const float* __restrict__ W1,
    const float* __restrict__ W2, const float* __restrict__ bias,
    const float* __restrict__ v_w, const float* __restrict__ v_b,
    float* __restrict__ attn,      // d_out + 2048
    float* __restrict__ ws_l,      // [NB*CHUNKS]
    float* __restrict__ ws_ctx)    // [NB*CHUNKS*16]
{
    const int b   = blockIdx.x >> 4;   // / CHUNKS
    const int c   = blockIdx.x & 15;   // % CHUNKS
    const int tid = threadIdx.x;

    __shared__ float s_comb[DW];       // q_proj[w] + bias (block-uniform)
    __shared__ float s_rctx[4 * 16];   // per-wave partial ctx
    __shared__ float s_rl[4];

    // Issue this thread's 4 independent key float4 loads FIRST (overlap with
    // the comb preamble; single vmcnt wait before the w-loop).
    const size_t tbase = (size_t)b * NT + (size_t)c * TC + tid;  // this t
    const float4* kp = reinterpret_cast<const float4*>(key)   + tbase * 4;
    const float4* vp = reinterpret_cast<const float4*>(value) + tbase * 4;
    const float4 k0 = kp[0], k1 = kp[1], k2 = kp[2], k3 = kp[3];

    // Preamble: 32 lanes compute comb[w] = q.W1[w] + bias.
    if (tid < DW) {
        const int w = tid;
        float acc = bias[0];
        const float* q  = query + b * DKD;
        const float* w1 = W1 + w * DKD;
        #pragma unroll
        for (int d = 0; d < DKD; ++d) acc = fmaf(q[d], w1[d], acc);
        s_comb[w] = acc;
    }
    __syncthreads();

    const float vb = v_b[0];
    float sc = vb;

    // Fully unrolled w-loop: W2[w*16+d] / v_w[w] are wave-uniform constant
    // indices -> scalar loads (constant cache); comb[w] is an LDS broadcast.
    #pragma unroll
    for (int w = 0; w < DW; ++w) {
        const float* wr = W2 + w * DKD;
        float h = s_comb[w];
        h = fmaf(k0.x, wr[ 0], h); h = fmaf(k0.y, wr[ 1], h);
        h = fmaf(k0.z, wr[ 2], h); h = fmaf(k0.w, wr[ 3], h);
        h = fmaf(k1.x, wr[ 4], h); h = fmaf(k1.y, wr[ 5], h);
        h = fmaf(k1.z, wr[ 6], h); h = fmaf(k1.w, wr[ 7], h);
        h = fmaf(k2.x, wr[ 8], h); h = fmaf(k2.y, wr[ 9], h);
        h = fmaf(k2.z, wr[10], h); h = fmaf(k2.w, wr[11], h);
        h = fmaf(k3.x, wr[12], h); h = fmaf(k3.y, wr[13], h);
        h = fmaf(k3.z, wr[14], h); h = fmaf(k3.w, wr[15], h);
        sc = fmaf(fast_tanh(h), v_w[w], sc);
    }

    const float p = __expf(sc);
    attn[(size_t)b * NT + (size_t)c * TC + tid] = p;   // coalesced dword

    // 4 independent value float4 loads, immediately consumed.
    const float4 v0 = vp[0], v1 = vp[1], v2 = vp[2], v3 = vp[3];
    float ctx[16];
    ctx[ 0] = p * v0.x; ctx[ 1] = p * v0.y; ctx[ 2] = p * v0.z; ctx[ 3] = p * v0.w;
    ctx[ 4] = p * v1.x; ctx[ 5] = p * v1.y; ctx[ 6] = p * v1.z; ctx[ 7] = p * v1.w;
    ctx[ 8] = p * v2.x; ctx[ 9] = p * v2.y; ctx[10] = p * v2.z; ctx[11] = p * v2.w;
    ctx[12] = p * v3.x; ctx[13] = p * v3.y; ctx[14] = p * v3.z; ctx[15] = p * v3.w;

    // Block reduction: wave shuffle-reduce, then 4 waves via LDS.
    float l = p;
    #pragma unroll
    for (int o = 32; o > 0; o >>= 1) l += __shfl_xor(l, o);
    #pragma unroll
    for (int d = 0; d < 16; ++d) {
        #pragma unroll
        for (int o = 32; o > 0; o >>= 1) ctx[d] += __shfl_xor(ctx[d], o);
    }
    const int wave = tid >> 6;
    const int lane = tid & 63;
    if (lane == 0) {
        s_rl[wave] = l;
        #pragma unroll
        for (int d = 0; d < 16; ++d) s_rctx[wave * 16 + d] = ctx[d];
    }
    __syncthreads();
    const int slot = b * CHUNKS + c;
    if (tid < 16)
        ws_ctx[slot * 16 + tid] =
            s_rctx[tid] + s_rctx[16 + tid] + s_rctx[32 + tid] + s_rctx[48 + tid];
    if (tid == 0)
        ws_l[slot] = s_rl[0] + s_rl[1] + s_rl[2] + s_rl[3];
}

// Kernel 2: normalize attn in place by 1/L and write context.
// Grid NB*8 blocks x 128 threads; each thread one float4 (512 elems/block).
__global__ __launch_bounds__(BLK2) void aa_finish(
    float* __restrict__ out,          // [0,2048) context, [2048,...) attn
    const float* __restrict__ ws_l,
    const float* __restrict__ ws_ctx)
{
    const int b   = blockIdx.x >> 3;
    const int seg = blockIdx.x & 7;
    const int tid = threadIdx.x;
    float L = 0.0f;
    #pragma unroll
    for (int i = 0; i < CHUNKS; ++i) L += ws_l[b * CHUNKS + i];
    const float inv = 1.0f / L;

    float4* ap = reinterpret_cast<float4*>(out + NB*DKD + (size_t)b * NT + (size_t)seg * 512);
    float4 p = ap[tid];
    p.x *= inv; p.y *= inv; p.z *= inv; p.w *= inv;
    ap[tid] = p;

    if (seg == 0 && tid < DKD) {
        const float* wc = ws_ctx + b * CHUNKS * 16;
        float s = 0.0f;
        #pragma unroll
        for (int i = 0; i < CHUNKS; ++i) s += wc[i * 16 + tid];
        out[b * DKD + tid] = s * inv;
    }
}

extern "C" void kernel_launch(void* const* d_in, const int* in_sizes, int n_in,
                              void* d_out, int out_size, void* d_ws, size_t ws_size,
                              hipStream_t stream) {
    const float* query = (const float*)d_in[0];
    const float* key   = (const float*)d_in[1];
    const float* value = (const float*)d_in[2];
    const float* W1    = (const float*)d_in[3];
    const float* W2    = (const float*)d_in[4];
    const float* bias  = (const float*)d_in[5];
    const float* v_w   = (const float*)d_in[6];
    const float* v_b   = (const float*)d_in[7];
    float* out = (float*)d_out;

    float* ws_l   = (float*)d_ws;          // NB*CHUNKS floats
    float* ws_ctx = ws_l + NB * CHUNKS;    // NB*CHUNKS*16 floats

    aa_score<<<NB * CHUNKS, BLK, 0, stream>>>(
        query, key, value, W1, W2, bias, v_w, v_b,
        out + NB * DKD, ws_l, ws_ctx);
    aa_finish<<<NB * 8, BLK2, 0, stream>>>(out, ws_l, ws_ctx);
}